// Round 8
// baseline (383.335 us; speedup 1.0000x reference)
//
#include <hip/hip_runtime.h>
#include <hip/hip_bf16.h>
#include <stdint.h>

// GRUModel: y[t,b,:] = GRUCell(x[t,b,:], hid[t,b,:]) per (t,b). M = T*B = 131072, H = I = 128.
//
// v8: r7's DMA-ring structure with the cls-split REMOVED: one 512-thread block (8 waves) owns
// all 128 h-cols, so each 16KB tile is DMA'd once (r7: twice -> 2x DMA issue, L2 traffic,
// LDS-write BW, and 2x per-CU block-tiles). Per-CU block-tiles 64 -> 32; waves/CU 8 -> 16
// (launch_bounds(512,4) pins VGPR<=128; r7 measured 120 with identical register structure).
//   - 4-slot LDS ring (4 x 16KB fp32: x 8KB | hid 8KB), global_load_lds fills (linear dest,
//     XOR-swizzle pre-applied on per-lane GLOBAL source). 3 tiles of loads always in flight.
//   - Steady iter: s_waitcnt vmcnt(10) -> s_barrier -> ISSUE(t+3) -> COMPUTE(t).
//     Per wave per iter: 2 loads + 2 stores; exact-minimal counted waits (in-order retirement):
//     head 4,6,8; steady 10; tail 10,8,6. vmcnt never drained to 0 in the loop.
//   - Slot reuse distance 4; ISSUE(t+3) only after the barrier that proves all waves finished
//     COMPUTE(t-1) (the slot's last reader). Verified structure (r7 passed).
//   - hv (blend) + hout served from the LDS hid tile (exact fp32 round trip); y/hout f32x4 stores.
//   - Consumer per wave: fp32 frag ds_read pairs (swizzled), pack to bf16, 24 MFMA
//     (weights-as-A resident in VGPRs, layout verified r2-r7), rcpf gate epilogue.

typedef __attribute__((ext_vector_type(8))) short short8;    // 8 bf16 = 4 VGPRs
typedef __attribute__((ext_vector_type(4))) float f32x4;

#define WAITV(N) asm volatile("s_waitcnt vmcnt(" #N ")" ::: "memory")
#define BAR() do { asm volatile("" ::: "memory"); \
                   __builtin_amdgcn_s_barrier();  \
                   asm volatile("" ::: "memory"); } while (0)

__device__ __forceinline__ float rcpf(float v) { return __builtin_amdgcn_rcpf(v); }
__device__ __forceinline__ float fast_sigmoid(float v) {
    return rcpf(1.0f + __expf(-v));
}
__device__ __forceinline__ float fast_tanh(float v) {
    return 2.0f * rcpf(1.0f + __expf(-2.0f * v)) - 1.0f;  // inf-safe
}

// fp32 -> bf16 (RNE) via HW cvt; compiler packs pairs into v_cvt_pk_bf16_f32
__device__ __forceinline__ short f2bf(float f) {
    union { __hip_bfloat16 b; short s; } u; u.b = __float2bfloat16(f);
    return u.s;
}
__device__ __forceinline__ short8 pack8(f32x4 a, f32x4 b) {
    short8 r;
    r[0] = f2bf(a[0]); r[1] = f2bf(a[1]); r[2] = f2bf(a[2]); r[3] = f2bf(a[3]);
    r[4] = f2bf(b[0]); r[5] = f2bf(b[1]); r[6] = f2bf(b[2]); r[7] = f2bf(b[3]);
    return r;
}

// issue one tile's 16 global_load_lds (this wave's 2): per-lane global src (pre-swizzled),
// wave-uniform LDS dest base (HW adds lane*16).
#define ISSUE(T) do {                                                           \
    const float* tb_ = opsrc + (size_t)(T) * 2048;                              \
    char*        lb_ = lds + (((T) & 3) * 16384) + ldsbase;                     \
    _Pragma("unroll")                                                           \
    for (int j_ = 0; j_ < 2; ++j_) {                                            \
        __builtin_amdgcn_global_load_lds(                                       \
            (const __attribute__((address_space(1))) void*)(tb_ + soff[j_]),    \
            (__attribute__((address_space(3))) void*)(lb_ + j_ * 1024),         \
            16, 0, 0);                                                          \
    }                                                                           \
} while (0)

// compute one tile from its ring slot: frag reads + cvt + 24 MFMA + epilogue + y/hout stores
#define COMPUTE(T) do {                                                         \
    char* sb_ = lds + (((T) & 3) * 16384);                                      \
    f32x4 acc[6];                                                               \
    _Pragma("unroll")                                                           \
    for (int g_ = 0; g_ < 6; ++g_) acc[g_] = (f32x4){0.f, 0.f, 0.f, 0.f};       \
    _Pragma("unroll")                                                           \
    for (int s_ = 0; s_ < 4; ++s_) {                                            \
        f32x4 x0_ = *(const f32x4*)(sb_ + fro[s_][0]);                          \
        f32x4 x1_ = *(const f32x4*)(sb_ + fro[s_][1]);                          \
        f32x4 h0_ = *(const f32x4*)(sb_ + 8192 + fro[s_][0]);                   \
        f32x4 h1_ = *(const f32x4*)(sb_ + 8192 + fro[s_][1]);                   \
        short8 xa_ = pack8(x0_, x1_);                                           \
        short8 ha_ = pack8(h0_, h1_);                                           \
        acc[0] = __builtin_amdgcn_mfma_f32_16x16x32_bf16(wf[0][s_], xa_, acc[0], 0, 0, 0); \
        acc[1] = __builtin_amdgcn_mfma_f32_16x16x32_bf16(wf[1][s_], xa_, acc[1], 0, 0, 0); \
        acc[2] = __builtin_amdgcn_mfma_f32_16x16x32_bf16(wf[2][s_], xa_, acc[2], 0, 0, 0); \
        acc[3] = __builtin_amdgcn_mfma_f32_16x16x32_bf16(wf[3][s_], ha_, acc[3], 0, 0, 0); \
        acc[4] = __builtin_amdgcn_mfma_f32_16x16x32_bf16(wf[4][s_], ha_, acc[4], 0, 0, 0); \
        acc[5] = __builtin_amdgcn_mfma_f32_16x16x32_bf16(wf[5][s_], ha_, acc[5], 0, 0, 0); \
    }                                                                           \
    f32x4 hv_ = *(const f32x4*)(sb_ + 8192 + hvoff);   /* exact fp32 hid */     \
    f32x4 hc_ = *(const f32x4*)(sb_ + 8192 + hooff);   /* hout chunk */         \
    f32x4 yv_;                                                                  \
    _Pragma("unroll")                                                           \
    for (int r_ = 0; r_ < 4; ++r_) {                                            \
        float rv = fast_sigmoid(acc[0][r_] + acc[3][r_] + br4[r_]);             \
        float zv = fast_sigmoid(acc[1][r_] + acc[4][r_] + bz4[r_]);             \
        float nv = fast_tanh(acc[2][r_] + bin4[r_] + rv * (acc[5][r_] + bhn4[r_])); \
        yv_[r_] = (1.0f - zv) * nv + zv * hv_[r_];                              \
    }                                                                           \
    *(f32x4*)(y    + (size_t)(T) * 2048 + yoff)    = yv_;                       \
    *(f32x4*)(hout + (size_t)(T) * 2048 + hooff_g) = hc_;                       \
} while (0)

__global__ __launch_bounds__(512, 4) void gru_kernel(
    const float* __restrict__ x,
    const float* __restrict__ hid,
    const float* __restrict__ Wih,
    const float* __restrict__ Whh,
    const float* __restrict__ bih,
    const float* __restrict__ bhh,
    float* __restrict__ y,
    float* __restrict__ hout,
    int ntiles, int tpb)
{
    // ring: 4 slots x [x fp32 16x128 (8KB) | hid fp32 16x128 (8KB)]; rows 512B,
    // 16B-chunk swizzle cc^(row&7) applied on global src + all LDS reads.
    __shared__ __align__(16) char lds[4 * 16384];    // 64 KB

    const int tid  = threadIdx.x;
    const int lane = tid & 63;
    const int w    = tid >> 6;       // wave 0..7 -> h-cols w*16 .. w*16+15
    const int l15  = lane & 15;
    const int q    = lane >> 4;      // quad 0..3

    const int t0 = blockIdx.x * tpb;
    const int t1 = (t0 + tpb < ntiles) ? (t0 + tpb) : ntiles;
    if (t0 >= t1) return;
    const int nt = t1 - t0;

    // ---- weights -> VGPR A-fragments (L2/L3-resident source; layout verified r2-r7) ----
    short8 wf[6][4];                 // g = {i_r,i_z,i_n,h_r,h_z,h_n}
    #pragma unroll
    for (int g = 0; g < 6; ++g) {
        const float* Wp  = (g < 3) ? Wih : Whh;
        const float* src = Wp + (size_t)((g % 3) * 128 + w * 16 + l15) * 128 + q * 8;
        #pragma unroll
        for (int s = 0; s < 4; ++s) {
            f32x4 a = *(const f32x4*)(src + s * 32);
            f32x4 b = *(const f32x4*)(src + s * 32 + 4);
            wf[g][s] = pack8(a, b);
        }
    }

    // ---- per-lane biases for this lane's 4 h-cols ----
    const int h0 = w * 16 + q * 4;
    f32x4 br4  = *(const f32x4*)(bih + h0)       + *(const f32x4*)(bhh + h0);
    f32x4 bz4  = *(const f32x4*)(bih + 128 + h0) + *(const f32x4*)(bhh + 128 + h0);
    f32x4 bin4 = *(const f32x4*)(bih + 256 + h0);
    f32x4 bhn4 = *(const f32x4*)(bhh + 256 + h0);

    // ---- producer geometry: waves 0-3 -> x, waves 4-7 -> hid; 2 DMA instrs/wave/tile ----
    const float*   opsrc   = (w < 4) ? x : hid;
    const int      i0      = (w & 3) * 2;                       // instr idx within operand
    const unsigned ldsbase = (unsigned)(w >> 2) * 8192u + (unsigned)i0 * 1024u;
    int soff[2];                     // per-lane pre-swizzled global float offsets
    #pragma unroll
    for (int j = 0; j < 2; ++j) {
        int row = 2 * (i0 + j) + (lane >> 5);   // tile row 0..15
        int cc  = lane & 31;                    // 16B chunk in row
        soff[j] = row * 128 + ((cc ^ (row & 7)) * 4);
    }

    // ---- consumer offsets (all swizzled to match) ----
    int fro[4][2];                   // fragment reads: row l15, chunks s*8+q*2 (+1)
    #pragma unroll
    for (int s = 0; s < 4; ++s) {
        #pragma unroll
        for (int hhi = 0; hhi < 2; ++hhi) {
            int cc = s * 8 + q * 2 + hhi;
            fro[s][hhi] = l15 * 512 + ((cc ^ (l15 & 7)) * 16);
        }
    }
    const int hvoff = l15 * 512 + (((w * 4 + q) ^ (l15 & 7)) * 16);

    // hout: 512 threads cover the 16x128 tile; thread tid -> chunk (row tid>>5, cc tid&31)
    const int row_o   = tid >> 5;
    const int cc_o    = tid & 31;
    const int hooff   = row_o * 512 + ((cc_o ^ (row_o & 7)) * 16);  // LDS byte (hid region)
    const int hooff_g = row_o * 128 + cc_o * 4;                     // global float
    const int yoff    = l15 * 128 + h0;                             // global float

    if (nt >= 6) {
        ISSUE(t0); ISSUE(t0 + 1); ISSUE(t0 + 2);
        // exact-minimal counted waits (2 loads + 2 stores per wave per iter, in-order):
        WAITV(4);  BAR(); ISSUE(t0 + 3); COMPUTE(t0);
        WAITV(6);  BAR(); ISSUE(t0 + 4); COMPUTE(t0 + 1);
        WAITV(8);  BAR(); ISSUE(t0 + 5); COMPUTE(t0 + 2);
        for (int t = t0 + 3; t < t1 - 3; ++t) {
            WAITV(10); BAR(); ISSUE(t + 3); COMPUTE(t);
        }
        WAITV(10); BAR(); COMPUTE(t1 - 3);
        WAITV(8);  BAR(); COMPUTE(t1 - 2);
        WAITV(6);  BAR(); COMPUTE(t1 - 1);
    } else {
        // small-tail fallback (not hit at M=131072)
        for (int t = t0; t < t1; ++t) {
            ISSUE(t); WAITV(0); BAR(); COMPUTE(t);
        }
    }
}

extern "C" void kernel_launch(void* const* d_in, const int* in_sizes, int n_in,
                              void* d_out, int out_size, void* d_ws, size_t ws_size,
                              hipStream_t stream) {
    const float* x   = (const float*)d_in[0];
    const float* hid = (const float*)d_in[1];
    const float* Wih = (const float*)d_in[2];
    const float* Whh = (const float*)d_in[3];
    const float* bih = (const float*)d_in[4];
    const float* bhh = (const float*)d_in[5];

    const int M = in_sizes[0] / 128;               // T*B = 131072
    float* y    = (float*)d_out;
    float* hout = y + (size_t)M * 128;

    const int ntiles = M / 16;                     // 8192 row-tiles
    const int tpb    = 16;
    const int grid   = (ntiles + tpb - 1) / tpb;   // 512 blocks (2/CU, all resident)

    gru_kernel<<<grid, 512, 0, stream>>>(x, hid, Wih, Whh, bih, bhh, y, hout, ntiles, tpb);
}